// Round 3
// baseline (424.479 us; speedup 1.0000x reference)
//
#include <hip/hip_runtime.h>
#include <hip/hip_cooperative_groups.h>
#include <math.h>

namespace cg = cooperative_groups;

#define N 512
#define H 128
#define L 4
#define NUM_RBF 50
#define NMOL 16
#define SUPER 64          // neighbor slots per super-tile
#define MAXS 8            // max super-tiles per node
#define NB 256            // blocks; block bid owns nodes bid and bid+NB

typedef __attribute__((ext_vector_type(8))) short short8;
typedef __attribute__((ext_vector_type(4))) float float4v;
typedef __attribute__((ext_vector_type(4))) int int4v;

__device__ __forceinline__ float silu_f(float v) {
    return v / (1.0f + __expf(-v));
}

__device__ __forceinline__ unsigned short f2bf(float f) {
    unsigned int u = __float_as_uint(f);
    unsigned int r = (u + 0x7FFFu + ((u >> 16) & 1u)) >> 16;  // RNE
    return (unsigned short)r;
}

// async 16B global->LDS copy. dst must be WAVE-UNIFORM; HW adds lane*16.
__device__ __forceinline__ void gld_lds16(const void* g, void* l) {
    __builtin_amdgcn_global_load_lds(
        (const __attribute__((address_space(1))) unsigned int*)g,
        (__attribute__((address_space(3))) unsigned int*)l, 16, 0, 0);
}

// ONE cooperative kernel for the whole net. 256 blocks x 512 threads,
// 1 block/CU guaranteed co-resident. Block bid owns nodes {bid, bid+256}.
// Phase 0: embed + neighbor compaction (LDS) + a0 + bf16 feature tiles -> Fg.
// Per layer: MFMA message pass (per node) + batched 2-node update MLP tail.
// grid.sync() between phases (5 total). x lives in LDS; written once at end.
__global__ __launch_bounds__(512) void k_all(
    const int* __restrict__ an, const float* __restrict__ pos,
    const int* __restrict__ batch, const float* __restrict__ embed,
    const float* __restrict__ msg_w1, const float* __restrict__ msg_b1,
    const float* __restrict__ msg_w2, const float* __restrict__ msg_b2,
    const float* __restrict__ upd_w1, const float* __restrict__ upd_b1,
    const float* __restrict__ upd_w2, const float* __restrict__ upd_b2,
    const float* __restrict__ ow1, const float* __restrict__ ob1,
    const float* __restrict__ ow2, const float* __restrict__ ob2,
    float* __restrict__ out,
    float* __restrict__ xg, float* __restrict__ a0g, float* __restrict__ a1g,
    unsigned short* __restrict__ Fg)
{
    cg::grid_group grid = cg::this_grid();
    const int bid = blockIdx.x;
    const int tid = threadIdx.x;
    const int lane = tid & 63;
    const int wave = tid >> 6;
    const int h128 = tid & 127;
    const int grp = tid >> 7;
    // msg-pass indices
    const int g = tid >> 8;          // wave-group 0..1
    const int wv4 = (tid >> 6) & 3;  // wave within group
    const int nn = lane & 15;
    const int quad = lane >> 4;
    const int hbase = wv4 * 32;

    __shared__ __align__(16) unsigned short F[2][2][SUPER * 64];  // 32 KB
    __shared__ __align__(16) int nidx[2][512];                    // 4 KB
    __shared__ float xcur[2][H];
    __shared__ float sjv[2][H], sjp[2][H];
    __shared__ float tp[4][H];
    __shared__ float agv[2][H], hidv[2][H];
    __shared__ int wsum8[8];
    __shared__ int cnt_s[2];
    __shared__ int lo_s, hi_s;

    // ---------------- phase 0: embed, compact, a0, features ----------------
    for (int n = 0; n < 2; n++) {
        const int j = bid + n * NB;
        const float pjx = pos[j * 3 + 0], pjy = pos[j * 3 + 1], pjz = pos[j * 3 + 2];

        if (tid < H) {
            int z = an[j];
            z = min(max(z, 0), 99);
            xcur[n][tid] = embed[z * H + tid];
        }

        int padded;
        {
            int i = tid;
            float dx = pos[i * 3 + 0] - pjx;
            float dy = pos[i * 3 + 1] - pjy;
            float dz = pos[i * 3 + 2] - pjz;
            float d2 = dx * dx + dy * dy + dz * dz;
            int valid = (d2 < 25.0f) && (i != j);
            unsigned long long m = __ballot(valid);
            int pre = __popcll(m & ((1ull << lane) - 1ull));
            if (lane == 0) wsum8[wave] = __popcll(m);
            __syncthreads();                 // S1: wsum8 + xcur[n] ready
            int wbase = 0, total = 0;
            for (int w = 0; w < 8; w++) {
                if (w < wave) wbase += wsum8[w];
                total += wsum8[w];
            }
            if (valid) nidx[n][wbase + pre] = i;
            padded = (total + 63) & ~63;
            for (int s = total + tid; s < padded; s += 512) nidx[n][s] = j;
            if (tid == 0) cnt_s[n] = total;
        }

        // a0 = b1 + xcur[n] @ Wx (layer-0 rows 0..127 of msg_w1), 4-way split-K
        {
            float p0 = 0.f, p1 = 0.f, p2 = 0.f, p3 = 0.f;
            int k0 = grp * 32;
#pragma unroll 8
            for (int k = 0; k < 32; k += 4) {
                p0 += xcur[n][k0 + k]     * msg_w1[(k0 + k)     * H + h128];
                p1 += xcur[n][k0 + k + 1] * msg_w1[(k0 + k + 1) * H + h128];
                p2 += xcur[n][k0 + k + 2] * msg_w1[(k0 + k + 2) * H + h128];
                p3 += xcur[n][k0 + k + 3] * msg_w1[(k0 + k + 3) * H + h128];
            }
            tp[grp][h128] = (p0 + p1) + (p2 + p3);
        }
        __syncthreads();                     // S2: nidx + tp ready
        if (grp == 0)
            a0g[j * H + h128] = tp[0][h128] + tp[1][h128] + tp[2][h128] + tp[3][h128] + msg_b1[h128];

        // features -> Fg: 4 threads per slot, 16 features each; XOR-chunk swizzle
        {
            const float DELTA = 5.0f / 49.0f;
            int kb = (tid & 3) * 16;
#pragma unroll
            for (int pass = 0; pass < 4; pass++) {
                int slot = pass * 128 + (tid >> 2);
                if (slot < padded) {
                    int ni = nidx[n][slot];
                    float dx = pos[ni * 3 + 0] - pjx;
                    float dy = pos[ni * 3 + 1] - pjy;
                    float dz = pos[ni * 3 + 2] - pjz;
                    float d = sqrtf(dx * dx + dy * dy + dz * dz);
                    float rinv = 1.0f / fmaxf(d, 1e-8f);
                    unsigned short vals[16];
#pragma unroll
                    for (int qq = 0; qq < 16; qq++) {
                        int k = kb + qq;
                        float v;
                        if (k < NUM_RBF) {
                            float tt = d - (float)k * DELTA;
                            v = __expf(-50.0f * tt * tt);
                        } else if (k == NUM_RBF)     v = dx * rinv;
                        else if (k == NUM_RBF + 1)   v = dy * rinv;
                        else if (k == NUM_RBF + 2)   v = dz * rinv;
                        else                         v = 0.0f;
                        vals[qq] = f2bf(v);
                    }
                    int row = slot & 63;
                    unsigned short* tile = Fg + (((size_t)(j * MAXS + (slot >> 6))) << 12);
                    int c0 = kb >> 3;
                    int4v p0, p1;
#pragma unroll
                    for (int q = 0; q < 4; q++) {
                        p0[q] = (int)((unsigned)vals[2 * q]     | ((unsigned)vals[2 * q + 1] << 16));
                        p1[q] = (int)((unsigned)vals[8 + 2 * q] | ((unsigned)vals[9 + 2 * q] << 16));
                    }
                    *(int4v*)(tile + row * 64 + (((c0    ) ^ (row & 7)) << 3)) = p0;
                    *(int4v*)(tile + row * 64 + (((c0 + 1) ^ (row & 7)) << 3)) = p1;
                }
            }
        }
        __syncthreads();                     // S3: free wsum8/tp for next node
    }
    grid.sync();   // a0 + Fg visible grid-wide

    // ---------------- layers ----------------
    const int W1R = H + NUM_RBF + 3;  // 181
    for (int l = 0; l < L; l++) {
        const float* wfeat = msg_w1 + l * W1R * H + H * H;
        const float* w2  = msg_w2 + l * H * H;
        const float* b2  = msg_b2 + l * H;
        const float* u1  = upd_w1 + l * 2 * H * H;
        const float* ub1 = upd_b1 + l * H;
        const float* u2  = upd_w2 + l * H * H;
        const float* ub2 = upd_b2 + l * H;
        const float* acur = (l & 1) ? a1g : a0g;
        float* anext = (l & 1) ? a0g : a1g;
        const float* wxn = msg_w1 + (l + 1) * W1R * H;  // used only if l < L-1
        const float* b1n = msg_b1 + (l + 1) * H;

        // B fragments for this layer's Wfeat
        short8 bfrag[2][2];
        for (int c = 0; c < 2; c++) {
            for (int t = 0; t < 2; t++) {
                short8 b;
                int hh = hbase + 16 * t + nn;
#pragma unroll
                for (int jj = 0; jj < 8; jj++) {
                    int k = c * 32 + quad * 8 + jj;
                    float v = (k < NUM_RBF + 3) ? wfeat[k * H + hh] : 0.0f;
                    b[jj] = (short)f2bf(v);
                }
                bfrag[c][t] = b;
            }
        }

        // ---- message pass per node ----
        for (int n = 0; n < 2; n++) {
            const int j = bid + n * NB;
            int cnt = cnt_s[n];
            int S = (cnt + 63) >> 6;
            int rounds = (S + 1) >> 1;

            auto stage_tile = [&](int s, int b) {
                const char* src = (const char*)(Fg + (((size_t)(j * MAXS + s)) << 12));
                char* dst = (char*)&F[g][b][0];
#pragma unroll
                for (int q = 0; q < 2; q++) {
                    int off = (wv4 + 4 * q) << 10;   // wave-uniform
                    gld_lds16(src + off + lane * 16, dst + off);
                }
            };

            if (g < S) stage_tile(g, 0);
            __syncthreads();

            float pacc0 = 0.0f, pacc1 = 0.0f;
            for (int r = 0; r < rounds; r++) {
                int s = 2 * r + g;
                int sn = 2 * (r + 1) + g;
                if (sn < S) stage_tile(sn, (r + 1) & 1);
                if (s < S) {
                    int cur = r & 1;
#pragma unroll
                    for (int it = 0; it < SUPER / 16; it++) {
                        int lbase = it * 16 + quad * 4;
                        int4v ni4 = *(const int4v*)&nidx[n][s * 64 + lbase];
                        float av0[4], av1[4];
#pragma unroll
                        for (int rr = 0; rr < 4; rr++) {
                            av0[rr] = acur[ni4[rr] * H + hbase + nn];
                            av1[rr] = acur[ni4[rr] * H + hbase + 16 + nn];
                        }
                        int row = it * 16 + nn;
                        const char* fb = (const char*)&F[g][cur][0] + row * 128;
                        short8 af0 = *(const short8*)(fb + ((quad       ^ (row & 7)) << 4));
                        short8 af1 = *(const short8*)(fb + (((quad + 4) ^ (row & 7)) << 4));
                        float4v acc0 = {0.0f, 0.0f, 0.0f, 0.0f};
                        float4v acc1 = {0.0f, 0.0f, 0.0f, 0.0f};
                        acc0 = __builtin_amdgcn_mfma_f32_16x16x32_bf16(af0, bfrag[0][0], acc0, 0, 0, 0);
                        acc0 = __builtin_amdgcn_mfma_f32_16x16x32_bf16(af1, bfrag[1][0], acc0, 0, 0, 0);
                        acc1 = __builtin_amdgcn_mfma_f32_16x16x32_bf16(af0, bfrag[0][1], acc1, 0, 0, 0);
                        acc1 = __builtin_amdgcn_mfma_f32_16x16x32_bf16(af1, bfrag[1][1], acc1, 0, 0, 0);
#pragma unroll
                        for (int rr = 0; rr < 4; rr++) {
                            float vm = (s * 64 + lbase + rr < cnt) ? 1.0f : 0.0f;
                            pacc0 += vm * silu_f(acc0[rr] + av0[rr]);
                            pacc1 += vm * silu_f(acc1[rr] + av1[rr]);
                        }
                    }
                }
                __syncthreads();
            }

            pacc0 += __shfl_xor(pacc0, 16, 64);
            pacc0 += __shfl_xor(pacc0, 32, 64);
            pacc1 += __shfl_xor(pacc1, 16, 64);
            pacc1 += __shfl_xor(pacc1, 32, 64);
            if (lane < 16) {
                sjp[g][hbase + lane]      = pacc0;
                sjp[g][hbase + 16 + lane] = pacc1;
            }
            __syncthreads();
            if (tid < H) sjv[n][tid] = sjp[0][tid] + sjp[1][tid];
            __syncthreads();
        }

        // ---- batched 2-node update tail: node = tid>>8, kh = 2-way split-K ----
        {
            int node = tid >> 8;
            int kh = (tid >> 7) & 1;
            int h = tid & 127;
            int ti = node * 2 + kh;
            int j = bid + node * NB;

            // ag = sj @ w2 + cnt*b2
            {
                int k0 = kh * 64;
                float p0 = 0.f, p1 = 0.f, p2 = 0.f, p3 = 0.f;
#pragma unroll 8
                for (int k = 0; k < 64; k += 4) {
                    p0 += sjv[node][k0 + k]     * w2[(k0 + k)     * H + h];
                    p1 += sjv[node][k0 + k + 1] * w2[(k0 + k + 1) * H + h];
                    p2 += sjv[node][k0 + k + 2] * w2[(k0 + k + 2) * H + h];
                    p3 += sjv[node][k0 + k + 3] * w2[(k0 + k + 3) * H + h];
                }
                tp[ti][h] = (p0 + p1) + (p2 + p3);
            }
            __syncthreads();
            if (kh == 0)
                agv[node][h] = tp[node * 2][h] + tp[node * 2 + 1][h] + (float)cnt_s[node] * b2[h];
            __syncthreads();

            // hid = silu([x | ag] @ u1 + ub1), K=256 split by kh
            {
                float p0 = 0.f, p1 = 0.f, p2 = 0.f, p3 = 0.f;
                const float* src = (kh == 0) ? &xcur[node][0] : &agv[node][0];
                const float* w = (kh == 0) ? u1 : (u1 + H * H);
#pragma unroll 8
                for (int k = 0; k < H; k += 4) {
                    p0 += src[k]     * w[(k)     * H + h];
                    p1 += src[k + 1] * w[(k + 1) * H + h];
                    p2 += src[k + 2] * w[(k + 2) * H + h];
                    p3 += src[k + 3] * w[(k + 3) * H + h];
                }
                tp[ti][h] = (p0 + p1) + (p2 + p3);
            }
            __syncthreads();
            if (kh == 0)
                hidv[node][h] = silu_f(tp[node * 2][h] + tp[node * 2 + 1][h] + ub1[h]);
            __syncthreads();

            // x' = x + hid @ u2 + ub2
            {
                int k0 = kh * 64;
                float p0 = 0.f, p1 = 0.f, p2 = 0.f, p3 = 0.f;
#pragma unroll 8
                for (int k = 0; k < 64; k += 4) {
                    p0 += hidv[node][k0 + k]     * u2[(k0 + k)     * H + h];
                    p1 += hidv[node][k0 + k + 1] * u2[(k0 + k + 1) * H + h];
                    p2 += hidv[node][k0 + k + 2] * u2[(k0 + k + 2) * H + h];
                    p3 += hidv[node][k0 + k + 3] * u2[(k0 + k + 3) * H + h];
                }
                tp[ti][h] = (p0 + p1) + (p2 + p3);
            }
            __syncthreads();
            if (kh == 0) {
                float xv = xcur[node][h] + tp[node * 2][h] + tp[node * 2 + 1][h] + ub2[h];
                xcur[node][h] = xv;
                if (l == L - 1) xg[j * H + h] = xv;   // global x only needed by pool
            }
            __syncthreads();

            // a_next = x' @ wxn + b1n
            if (l < L - 1) {
                int k0 = kh * 64;
                float p0 = 0.f, p1 = 0.f, p2 = 0.f, p3 = 0.f;
#pragma unroll 8
                for (int k = 0; k < 64; k += 4) {
                    p0 += xcur[node][k0 + k]     * wxn[(k0 + k)     * H + h];
                    p1 += xcur[node][k0 + k + 1] * wxn[(k0 + k + 1) * H + h];
                    p2 += xcur[node][k0 + k + 2] * wxn[(k0 + k + 2) * H + h];
                    p3 += xcur[node][k0 + k + 3] * wxn[(k0 + k + 3) * H + h];
                }
                tp[ti][h] = (p0 + p1) + (p2 + p3);
                __syncthreads();
                if (kh == 0)
                    anext[j * H + h] = tp[node * 2][h] + tp[node * 2 + 1][h] + b1n[h];
            }
        }
        grid.sync();
    }

    // ---------------- pool (blocks 0..15, m = bid) ----------------
    if (bid < NMOL) {
        int m = bid;
        int q = tid >> 7, h = tid & 127;
        if (tid == 0) {
            int a = 0, b = N;
            while (a < b) { int mid = (a + b) >> 1; if (batch[mid] < m) a = mid + 1; else b = mid; }
            lo_s = a;
            b = N;
            while (a < b) { int mid = (a + b) >> 1; if (batch[mid] < m + 1) a = mid + 1; else b = mid; }
            hi_s = a;
        }
        __syncthreads();
        int lo = lo_s, hi = hi_s;
        float s = 0.0f;
        for (int i = lo + q; i < hi; i += 4) s += xg[i * H + h];
        tp[q][h] = s;
        __syncthreads();
        if (q == 0)
            sjv[0][h] = (tp[0][h] + tp[1][h] + tp[2][h] + tp[3][h]) / (float)max(hi - lo, 1);
        __syncthreads();
        if (tid < H / 2) {
            float p0 = 0.f, p1 = 0.f;
            for (int k = 0; k < H; k += 2) {
                p0 += sjv[0][k]     * ow1[(k)     * (H / 2) + tid];
                p1 += sjv[0][k + 1] * ow1[(k + 1) * (H / 2) + tid];
            }
            hidv[0][tid] = silu_f(p0 + p1 + ob1[tid]);
        }
        __syncthreads();
        if (tid == 0) {
            float o = ob2[0];
            for (int k = 0; k < H / 2; k++) o += hidv[0][k] * ow2[k];
            out[m] = o;
        }
    }
}

extern "C" void kernel_launch(void* const* d_in, const int* in_sizes, int n_in,
                              void* d_out, int out_size, void* d_ws, size_t ws_size,
                              hipStream_t stream) {
    (void)in_sizes; (void)n_in; (void)out_size; (void)ws_size;
    const int*   an      = (const int*)d_in[0];
    const float* pos     = (const float*)d_in[1];
    const int*   batch   = (const int*)d_in[2];
    const float* embed   = (const float*)d_in[3];
    const float* msg_w1  = (const float*)d_in[4];   // L x 181 x 128
    const float* msg_b1  = (const float*)d_in[5];
    const float* msg_w2  = (const float*)d_in[6];   // L x 128 x 128
    const float* msg_b2  = (const float*)d_in[7];
    const float* upd_w1  = (const float*)d_in[8];   // L x 256 x 128
    const float* upd_b1  = (const float*)d_in[9];
    const float* upd_w2  = (const float*)d_in[10];  // L x 128 x 128
    const float* upd_b2  = (const float*)d_in[11];
    const float* out_w1  = (const float*)d_in[12];  // 128 x 64
    const float* out_b1  = (const float*)d_in[13];
    const float* out_w2  = (const float*)d_in[14];  // 64 x 1
    const float* out_b2  = (const float*)d_in[15];
    float* out = (float*)d_out;

    float* xg  = (float*)d_ws;                          // N*H
    float* a0g = xg + N * H;                            // N*H (even layers)
    float* a1g = a0g + N * H;                           // N*H (odd layers)
    unsigned short* Fg = (unsigned short*)(a1g + N * H); // N*MAXS*64*64 bf16 (32 MB)

    void* args[] = {
        (void*)&an, (void*)&pos, (void*)&batch, (void*)&embed,
        (void*)&msg_w1, (void*)&msg_b1, (void*)&msg_w2, (void*)&msg_b2,
        (void*)&upd_w1, (void*)&upd_b1, (void*)&upd_w2, (void*)&upd_b2,
        (void*)&out_w1, (void*)&out_b1, (void*)&out_w2, (void*)&out_b2,
        (void*)&out, (void*)&xg, (void*)&a0g, (void*)&a1g, (void*)&Fg
    };
    hipLaunchCooperativeKernel((const void*)k_all, dim3(NB), dim3(512), args, 0u, stream);
}

// Round 4
// 201.333 us; speedup vs baseline: 2.1083x; 2.1083x over previous
//
#include <hip/hip_runtime.h>
#include <math.h>

#define N 512
#define H 128
#define L 4
#define NUM_RBF 50
#define NMOL 16
#define SUPER 64          // neighbor slots per super-tile
#define MAXS 8            // max super-tiles per node (ceil(511/64))

typedef __attribute__((ext_vector_type(8))) short short8;
typedef __attribute__((ext_vector_type(4))) float float4v;
typedef __attribute__((ext_vector_type(4))) int int4v;

// silu via v_rcp (1 ulp) instead of exact-div expansion (~8 instr, 2 trans-rate)
__device__ __forceinline__ float silu_f(float v) {
    return v * __builtin_amdgcn_rcpf(1.0f + __expf(-v));
}

__device__ __forceinline__ unsigned short f2bf(float f) {
    unsigned int u = __float_as_uint(f);
    unsigned int r = (u + 0x7FFFu + ((u >> 16) & 1u)) >> 16;  // RNE
    return (unsigned short)r;
}

// async 16B global->LDS copy. dst must be WAVE-UNIFORM; HW adds lane*16.
__device__ __forceinline__ void gld_lds16(const void* g, void* l) {
    __builtin_amdgcn_global_load_lds(
        (const __attribute__((address_space(1))) unsigned int*)g,
        (__attribute__((address_space(3))) unsigned int*)l, 16, 0, 0);
}

// Per block j (512 threads):
//  - ballot-compact valid neighbors (d<5, i!=j) into nbr[j*512..], pad to x64 with j
//  - x[j,h] = embed row;  a[j,h] = b1[h] + x[j,:] @ Wx[:,h]  (4-way split-K)
//  - precompute layer-invariant bf16 feature tiles F (rbf+dirs, 53->64 padded)
//    per (j, supertile): 64 rows x 64 shorts, 16B-chunk XOR swizzle c^(r&7)
//    (linear LDS dest for global_load_lds + conflict-optimal ds_read_b128).
__global__ __launch_bounds__(512) void k_embed_lin(const int* __restrict__ an,
                                                   const float* __restrict__ embed,
                                                   const float* __restrict__ pos,
                                                   const float* __restrict__ wx,
                                                   const float* __restrict__ b1,
                                                   float* __restrict__ x,
                                                   float* __restrict__ a,
                                                   int* __restrict__ nbr,
                                                   int* __restrict__ ncnt,
                                                   unsigned short* __restrict__ Fg) {
    int j = blockIdx.x;
    int tid = threadIdx.x;
    int lane = tid & 63;
    int wave = tid >> 6;
    int h = tid & 127;
    int grp = tid >> 7;

    __shared__ float xs[H];
    __shared__ int wsum8[8];
    __shared__ float part[4][H];

    float pjx = pos[j * 3 + 0], pjy = pos[j * 3 + 1], pjz = pos[j * 3 + 2];

    if (tid < H) {
        int z = an[j];
        z = min(max(z, 0), 99);
        float xv = embed[z * H + tid];
        xs[tid] = xv;
        x[j * H + tid] = xv;
    }

    int padded;
    {
        int i = tid;
        float dx = pos[i * 3 + 0] - pjx;
        float dy = pos[i * 3 + 1] - pjy;
        float dz = pos[i * 3 + 2] - pjz;
        float d2 = dx * dx + dy * dy + dz * dz;
        int valid = (d2 < 25.0f) && (i != j);
        unsigned long long m = __ballot(valid);
        int pre = __popcll(m & ((1ull << lane) - 1ull));
        if (lane == 0) wsum8[wave] = __popcll(m);
        __syncthreads();
        int wbase = 0, total = 0;
        for (int w = 0; w < 8; w++) {
            if (w < wave) wbase += wsum8[w];
            total += wsum8[w];
        }
        if (valid) nbr[j * 512 + wbase + pre] = i;
        padded = (total + 63) & ~63;
        for (int s = total + tid; s < padded; s += 512) nbr[j * 512 + s] = j;
        if (tid == 0) ncnt[j] = total;
    }

    // a = b1 + xs @ Wx, 4-way split-K
    {
        float p0 = 0.f, p1 = 0.f, p2 = 0.f, p3 = 0.f;
        int k0 = grp * 32;
#pragma unroll 8
        for (int k = 0; k < 32; k += 4) {
            p0 += xs[k0 + k]     * wx[(k0 + k)     * H + h];
            p1 += xs[k0 + k + 1] * wx[(k0 + k + 1) * H + h];
            p2 += xs[k0 + k + 2] * wx[(k0 + k + 2) * H + h];
            p3 += xs[k0 + k + 3] * wx[(k0 + k + 3) * H + h];
        }
        part[grp][h] = (p0 + p1) + (p2 + p3);
    }
    __syncthreads();   // part ready; nbr writes visible block-wide
    if (grp == 0)
        a[j * H + h] = part[0][h] + part[1][h] + part[2][h] + part[3][h] + b1[h];

    // ---- F feature precompute: 4 threads per slot, 16 features each ----
    const float DELTA = 5.0f / 49.0f;
    int kb = (tid & 3) * 16;
#pragma unroll
    for (int pass = 0; pass < 4; pass++) {
        int slot = pass * 128 + (tid >> 2);
        if (slot < padded) {
            int ni = nbr[j * 512 + slot];
            float dx = pos[ni * 3 + 0] - pjx;
            float dy = pos[ni * 3 + 1] - pjy;
            float dz = pos[ni * 3 + 2] - pjz;
            float d = sqrtf(dx * dx + dy * dy + dz * dz);
            float rinv = 1.0f / fmaxf(d, 1e-8f);
            unsigned short vals[16];
#pragma unroll
            for (int qq = 0; qq < 16; qq++) {
                int k = kb + qq;
                float v;
                if (k < NUM_RBF) {
                    float tt = d - (float)k * DELTA;
                    v = __expf(-50.0f * tt * tt);      // 1/(2*0.1^2) = 50
                } else if (k == NUM_RBF)     v = dx * rinv;
                else if (k == NUM_RBF + 1)   v = dy * rinv;
                else if (k == NUM_RBF + 2)   v = dz * rinv;
                else                         v = 0.0f;
                vals[qq] = f2bf(v);
            }
            int row = slot & 63;
            unsigned short* tile = Fg + (((size_t)(j * MAXS + (slot >> 6))) << 12);
            int c0 = kb >> 3;          // 16B-chunk index (8 shorts per chunk)
            int4v p0, p1;
#pragma unroll
            for (int q = 0; q < 4; q++) {
                p0[q] = (int)((unsigned)vals[2 * q]     | ((unsigned)vals[2 * q + 1] << 16));
                p1[q] = (int)((unsigned)vals[8 + 2 * q] | ((unsigned)vals[9 + 2 * q] << 16));
            }
            *(int4v*)(tile + row * 64 + (((c0    ) ^ (row & 7)) << 3)) = p0;
            *(int4v*)(tile + row * 64 + (((c0 + 1) ^ (row & 7)) << 3)) = p1;
        }
    }
}

// Fused per-layer kernel (R1 structure + cnt-balanced block->node mapping).
// Block b processes node j = order[rank], rank = b<256 ? b : 767-b, where
// order[] sorts nodes by ascending neighbor count. Under gfx950 dispatch
// (XCD = b%8, linear fill) blocks b and b+256 co-reside on one CU [m09],
// so each CU gets rank r + rank 511-r => near-constant per-CU work.
// Layer 0 (order_in==null): each block computes the rank sort locally from
// ncnt (~0.3us); block 0 publishes order_out for layers 1..3.
__global__ __launch_bounds__(512) void k_layer(const float* __restrict__ a,
                                               const int* __restrict__ nbr,
                                               const int* __restrict__ ncnt,
                                               const unsigned short* __restrict__ Fg,
                                               const float* __restrict__ wfeat,
                                               const float* __restrict__ w2,
                                               const float* __restrict__ b2,
                                               const float* __restrict__ u1,
                                               const float* __restrict__ ub1,
                                               const float* __restrict__ u2,
                                               const float* __restrict__ ub2,
                                               float* __restrict__ x,
                                               const float* __restrict__ wxn,
                                               const float* __restrict__ b1n,
                                               float* __restrict__ a_next,
                                               const int* __restrict__ order_in,
                                               int* __restrict__ order_out) {
    int b = blockIdx.x;
    int tid = threadIdx.x;
    int g = tid >> 8;          // wave-group 0..1
    int lane = tid & 63;
    int wv4 = (tid >> 6) & 3;  // wave within group
    int nn = lane & 15;
    int quad = lane >> 4;
    int hbase = wv4 * 32;

    __shared__ __align__(16) unsigned short F[2][2][SUPER * 64];  // [group][buf]
    __shared__ __align__(16) int nidx_all[512];
    __shared__ __align__(16) int cnts_l[512];
    __shared__ int order_l[512];
    __shared__ float sjp[2][H];
    __shared__ float sj[H], xj[H], ag[H], hid[H], xn[H];
    __shared__ float part[4][H];

    int rank = (b < 256) ? b : 767 - b;   // pair (b, b+256) -> ranks summing 511
    int j;
    if (order_in != nullptr) {
        j = order_in[rank];
    } else {
        cnts_l[tid] = ncnt[tid];
        __syncthreads();
        int c_t = cnts_l[tid];
        int r = 0;
#pragma unroll 4
        for (int i = 0; i < 512; i += 4) {
            int4v c4 = *(const int4v*)&cnts_l[i];
            r += (c4[0] < c_t || (c4[0] == c_t && (i    ) < tid)) ? 1 : 0;
            r += (c4[1] < c_t || (c4[1] == c_t && (i + 1) < tid)) ? 1 : 0;
            r += (c4[2] < c_t || (c4[2] == c_t && (i + 2) < tid)) ? 1 : 0;
            r += (c4[3] < c_t || (c4[3] == c_t && (i + 3) < tid)) ? 1 : 0;
        }
        order_l[r] = tid;      // strict total order -> bijection
        __syncthreads();
        j = order_l[rank];
        if (order_out != nullptr && b == 0) order_out[tid] = order_l[tid];
    }

    int cnt = ncnt[j];

    if (tid < 2 * H) sjp[tid >> 7][tid & 127] = 0.0f;
    if (tid < H) xj[tid] = x[j * H + tid];
    nidx_all[tid] = nbr[j * 512 + tid];   // all 512 slots, once

    // B fragments: loop-invariant. B[k = 32c + quad*8+jj][n = hbase + 16t + nn]
    short8 bfrag[2][2];
    for (int c = 0; c < 2; c++) {
        for (int t = 0; t < 2; t++) {
            short8 bb;
            int h = hbase + 16 * t + nn;
#pragma unroll
            for (int jj = 0; jj < 8; jj++) {
                int k = c * 32 + quad * 8 + jj;
                float v = (k < NUM_RBF + 3) ? wfeat[k * H + h] : 0.0f;
                bb[jj] = (short)f2bf(v);
            }
            bfrag[c][t] = bb;
        }
    }

    int S = (cnt + 63) >> 6;
    int rounds = (S + 1) >> 1;

    // stage one 8KB F tile (64x64 shorts) into F[g][b] via 8 async 1KB copies
    auto stage_tile = [&](int s, int buf) {
        const char* src = (const char*)(Fg + (((size_t)(j * MAXS + s)) << 12));
        char* dst = (char*)&F[g][buf][0];
#pragma unroll
        for (int q = 0; q < 2; q++) {
            int off = (wv4 + 4 * q) << 10;           // wave-uniform
            gld_lds16(src + off + lane * 16, dst + off);
        }
    };

    // prologue: stage s = g into buf 0
    if (g < S) stage_tile(g, 0);
    __syncthreads();   // drains vmcnt -> buf 0 ready, nidx_all ready

    float pacc0 = 0.0f, pacc1 = 0.0f;

    for (int r = 0; r < rounds; r++) {
        int s = 2 * r + g;
        int sn = 2 * (r + 1) + g;
        if (sn < S) stage_tile(sn, (r + 1) & 1);   // async, in flight under compute
        if (s < S) {
            int cur = r & 1;
#pragma unroll
            for (int it = 0; it < SUPER / 16; it++) {
                int lbase = it * 16 + quad * 4;
                int4v ni4 = *(const int4v*)&nidx_all[s * 64 + lbase];
                float av0[4], av1[4];
#pragma unroll
                for (int rr = 0; rr < 4; rr++) {
                    av0[rr] = a[ni4[rr] * H + hbase + nn];
                    av1[rr] = a[ni4[rr] * H + hbase + 16 + nn];
                }
                int row = it * 16 + nn;
                const char* fb = (const char*)&F[g][cur][0] + row * 128;
                short8 afrag0 = *(const short8*)(fb + ((quad       ^ (row & 7)) << 4));
                short8 afrag1 = *(const short8*)(fb + (((quad + 4) ^ (row & 7)) << 4));
                float4v acc0 = {0.0f, 0.0f, 0.0f, 0.0f};
                float4v acc1 = {0.0f, 0.0f, 0.0f, 0.0f};
                acc0 = __builtin_amdgcn_mfma_f32_16x16x32_bf16(afrag0, bfrag[0][0], acc0, 0, 0, 0);
                acc0 = __builtin_amdgcn_mfma_f32_16x16x32_bf16(afrag1, bfrag[1][0], acc0, 0, 0, 0);
                acc1 = __builtin_amdgcn_mfma_f32_16x16x32_bf16(afrag0, bfrag[0][1], acc1, 0, 0, 0);
                acc1 = __builtin_amdgcn_mfma_f32_16x16x32_bf16(afrag1, bfrag[1][1], acc1, 0, 0, 0);
#pragma unroll
                for (int rr = 0; rr < 4; rr++) {
                    float vm = (s * 64 + lbase + rr < cnt) ? 1.0f : 0.0f;
                    pacc0 += vm * silu_f(acc0[rr] + av0[rr]);
                    pacc1 += vm * silu_f(acc1[rr] + av1[rr]);
                }
            }
        }
        __syncthreads();   // one barrier per round (also drains staged loads)
    }

    // group partial -> LDS (quad shuffle-reduce; lanes 0..15 of each wave write)
    pacc0 += __shfl_xor(pacc0, 16, 64);
    pacc0 += __shfl_xor(pacc0, 32, 64);
    pacc1 += __shfl_xor(pacc1, 16, 64);
    pacc1 += __shfl_xor(pacc1, 32, 64);
    if (lane < 16) {
        sjp[g][hbase + lane]      = pacc0;
        sjp[g][hbase + 16 + lane] = pacc1;
    }
    __syncthreads();
    if (tid < H) sj[tid] = sjp[0][tid] + sjp[1][tid];
    __syncthreads();

    // ---- inline update: 4-way split-K MLP on 512 threads ----
    int h = tid & 127;
    int grp = tid >> 7;   // 0..3

    {
        float p0 = 0.f, p1 = 0.f, p2 = 0.f, p3 = 0.f;
        int k0 = grp * 32;
#pragma unroll 8
        for (int k = 0; k < 32; k += 4) {
            p0 += sj[k0 + k]     * w2[(k0 + k)     * H + h];
            p1 += sj[k0 + k + 1] * w2[(k0 + k + 1) * H + h];
            p2 += sj[k0 + k + 2] * w2[(k0 + k + 2) * H + h];
            p3 += sj[k0 + k + 3] * w2[(k0 + k + 3) * H + h];
        }
        part[grp][h] = (p0 + p1) + (p2 + p3);
    }
    __syncthreads();
    if (grp == 0) ag[h] = part[0][h] + part[1][h] + part[2][h] + part[3][h] + (float)cnt * b2[h];
    __syncthreads();

    {
        const float* src = (grp < 2) ? xj : ag;
        int sbase = (grp & 1) * 64;
        int k0 = grp * 64;
        float p0 = 0.f, p1 = 0.f, p2 = 0.f, p3 = 0.f;
#pragma unroll 8
        for (int k = 0; k < 64; k += 4) {
            p0 += src[sbase + k]     * u1[(k0 + k)     * H + h];
            p1 += src[sbase + k + 1] * u1[(k0 + k + 1) * H + h];
            p2 += src[sbase + k + 2] * u1[(k0 + k + 2) * H + h];
            p3 += src[sbase + k + 3] * u1[(k0 + k + 3) * H + h];
        }
        part[grp][h] = (p0 + p1) + (p2 + p3);
    }
    __syncthreads();
    if (grp == 0) hid[h] = silu_f(part[0][h] + part[1][h] + part[2][h] + part[3][h] + ub1[h]);
    __syncthreads();

    {
        float p0 = 0.f, p1 = 0.f, p2 = 0.f, p3 = 0.f;
        int k0 = grp * 32;
#pragma unroll 8
        for (int k = 0; k < 32; k += 4) {
            p0 += hid[k0 + k]     * u2[(k0 + k)     * H + h];
            p1 += hid[k0 + k + 1] * u2[(k0 + k + 1) * H + h];
            p2 += hid[k0 + k + 2] * u2[(k0 + k + 2) * H + h];
            p3 += hid[k0 + k + 3] * u2[(k0 + k + 3) * H + h];
        }
        part[grp][h] = (p0 + p1) + (p2 + p3);
    }
    __syncthreads();
    if (grp == 0) {
        float xv = xj[h] + part[0][h] + part[1][h] + part[2][h] + part[3][h] + ub2[h];
        x[j * H + h] = xv;
        xn[h] = xv;
    }

    if (a_next != nullptr) {
        __syncthreads();
        float p0 = 0.f, p1 = 0.f, p2 = 0.f, p3 = 0.f;
        int k0 = grp * 32;
#pragma unroll 8
        for (int k = 0; k < 32; k += 4) {
            p0 += xn[k0 + k]     * wxn[(k0 + k)     * H + h];
            p1 += xn[k0 + k + 1] * wxn[(k0 + k + 1) * H + h];
            p2 += xn[k0 + k + 2] * wxn[(k0 + k + 2) * H + h];
            p3 += xn[k0 + k + 3] * wxn[(k0 + k + 3) * H + h];
        }
        part[grp][h] = (p0 + p1) + (p2 + p3);
        __syncthreads();
        if (grp == 0)
            a_next[j * H + h] = part[0][h] + part[1][h] + part[2][h] + part[3][h] + b1n[h];
    }
}

// per-molecule mean pool + 2-layer output MLP. batch is SORTED (reference does
// jnp.sort): binary-search the [lo,hi) row range per molecule. 512 threads:
// 4-way split of the row-sum to shorten the serial load chain.
__global__ __launch_bounds__(512) void k_pool(const float* __restrict__ x,
                                              const int* __restrict__ batch,
                                              const float* __restrict__ ow1,
                                              const float* __restrict__ ob1,
                                              const float* __restrict__ ow2,
                                              const float* __restrict__ ob2,
                                              float* __restrict__ out) {
    int m = blockIdx.x;
    int tid = threadIdx.x;
    int h = tid & 127;
    int q = tid >> 7;
    __shared__ int lo_s, hi_s;
    __shared__ float psum[4][H];
    __shared__ float pooled[H];
    __shared__ float hid[H / 2];

    if (tid == 0) {
        int a = 0, b = N;
        while (a < b) { int mid = (a + b) >> 1; if (batch[mid] < m) a = mid + 1; else b = mid; }
        lo_s = a;
        b = N;
        while (a < b) { int mid = (a + b) >> 1; if (batch[mid] < m + 1) a = mid + 1; else b = mid; }
        hi_s = a;
    }
    __syncthreads();

    int lo = lo_s, hi = hi_s;
    float s = 0.0f;
    for (int i = lo + q; i < hi; i += 4) s += x[i * H + h];
    psum[q][h] = s;
    __syncthreads();
    if (q == 0) pooled[h] = (psum[0][h] + psum[1][h] + psum[2][h] + psum[3][h]) / (float)max(hi - lo, 1);
    __syncthreads();

    if (tid < H / 2) {
        float p0 = 0.f, p1 = 0.f;
        for (int k = 0; k < H; k += 2) {
            p0 += pooled[k]     * ow1[(k)     * (H / 2) + h];
            p1 += pooled[k + 1] * ow1[(k + 1) * (H / 2) + h];
        }
        hid[h] = silu_f(p0 + p1 + ob1[h]);
    }
    __syncthreads();

    if (tid == 0) {
        float o = ob2[0];
        for (int k = 0; k < H / 2; k++) o += hid[k] * ow2[k];
        out[m] = o;
    }
}

extern "C" void kernel_launch(void* const* d_in, const int* in_sizes, int n_in,
                              void* d_out, int out_size, void* d_ws, size_t ws_size,
                              hipStream_t stream) {
    const int*   an      = (const int*)d_in[0];
    const float* pos     = (const float*)d_in[1];
    const int*   batch   = (const int*)d_in[2];
    const float* embed   = (const float*)d_in[3];
    const float* msg_w1  = (const float*)d_in[4];   // L x 181 x 128
    const float* msg_b1  = (const float*)d_in[5];
    const float* msg_w2  = (const float*)d_in[6];   // L x 128 x 128
    const float* msg_b2  = (const float*)d_in[7];
    const float* upd_w1  = (const float*)d_in[8];   // L x 256 x 128
    const float* upd_b1  = (const float*)d_in[9];
    const float* upd_w2  = (const float*)d_in[10];  // L x 128 x 128
    const float* upd_b2  = (const float*)d_in[11];
    const float* out_w1  = (const float*)d_in[12];  // 128 x 64
    const float* out_b1  = (const float*)d_in[13];
    const float* out_w2  = (const float*)d_in[14];  // 64 x 1
    const float* out_b2  = (const float*)d_in[15];
    float* out = (float*)d_out;

    float* x    = (float*)d_ws;                         // N*H
    float* a0   = x + N * H;                            // N*H (even layers)
    float* a1   = a0 + N * H;                           // N*H (odd layers)
    int*   nbr  = (int*)(a1 + N * H);                   // N*512
    int*   ncnt = nbr + N * 512;                        // N
    int*   order_g = ncnt + N;                          // N (cnt-sorted node order)
    unsigned short* Fg = (unsigned short*)(order_g + N); // N*MAXS*64*64 bf16 (32 MB)

    const int W1ROWS = H + NUM_RBF + 3;  // 181

    k_embed_lin<<<N, 512, 0, stream>>>(an, embed, pos, msg_w1, msg_b1, x, a0, nbr, ncnt, Fg);
    for (int l = 0; l < L; l++) {
        float* a_cur  = (l & 1) ? a1 : a0;
        float* a_next = (l + 1 < L) ? ((l & 1) ? a0 : a1) : nullptr;
        const float* wxn = (l + 1 < L) ? (msg_w1 + (l + 1) * W1ROWS * H) : nullptr;
        const float* b1n = (l + 1 < L) ? (msg_b1 + (l + 1) * H) : nullptr;
        const int* oin  = (l == 0) ? nullptr : order_g;
        int*       oout = (l == 0) ? order_g : nullptr;
        k_layer<<<N, 512, 0, stream>>>(a_cur, nbr, ncnt, Fg,
                                       msg_w1 + l * W1ROWS * H + H * H,
                                       msg_w2 + l * H * H, msg_b2 + l * H,
                                       upd_w1 + l * 2 * H * H, upd_b1 + l * H,
                                       upd_w2 + l * H * H, upd_b2 + l * H,
                                       x, wxn, b1n, a_next, oin, oout);
    }
    k_pool<<<NMOL, 512, 0, stream>>>(x, batch, out_w1, out_b1, out_w2, out_b2, out);
}